// Round 9
// baseline (250.469 us; speedup 1.0000x reference)
//
#include <hip/hip_runtime.h>

typedef unsigned int u32;
typedef unsigned short u16;
typedef __attribute__((ext_vector_type(8))) __bf16 bf16x8;
typedef __attribute__((ext_vector_type(4))) float f32x4;

#define N_CAP 10
#define D_CAP 16
#define NN 160
#define KK 2048
#define NSTEPS 64           // global K-steps of 32 floats
#define SPLITK 2
#define LSTEPS 32           // K-steps per GEMM block (NSTEPS / SPLITK)
#define BMR 32              // rows per GEMM block
#define GTHREADS 320        // 5 waves (wjp 0..4)
#define BSTEP 20480         // bytes per K-step of Wpack
#define HATN (16384 * NN)   // floats per hat partial (10.5 MB)

// Pre-split W, lane-contiguous: 64 B per (s, wjp, lane) = [bh0|bh1|bl0|bl1]
// at Wpack_g[((s*5 + wjp)*64 + lane)*64 + v*16].
// bh0[j] = hi(W[32s + 8*(lane>>4) + j][32wjp + (lane&15)]), bh1: col+16,
// bl*: truncated low parts. 1.31 MB -> resident in every XCD L2.
__device__ __align__(16) unsigned char Wpack_g[NSTEPS * BSTEP];

__device__ __forceinline__ u32 pack_hi(float f0, float f1) {
  return __builtin_amdgcn_perm(__builtin_bit_cast(u32, f1),
                               __builtin_bit_cast(u32, f0), 0x07060302u);
}
__device__ __forceinline__ float hi_part(float f) {
  u32 u = __builtin_bit_cast(u32, f) & 0xFFFF0000u;
  return __builtin_bit_cast(float, u);
}
union U4B8 { uint4 u; bf16x8 b; };

__device__ __forceinline__ void split2(const float4& x, const float4& y,
                                       bf16x8& h, bf16x8& l) {
  U4B8 hh, ll;
  hh.u.x = pack_hi(x.x, x.y); hh.u.y = pack_hi(x.z, x.w);
  hh.u.z = pack_hi(y.x, y.y); hh.u.w = pack_hi(y.z, y.w);
  float l0 = x.x - hi_part(x.x), l1 = x.y - hi_part(x.y);
  float l2 = x.z - hi_part(x.z), l3 = x.w - hi_part(x.w);
  float l4 = y.x - hi_part(y.x), l5 = y.y - hi_part(y.y);
  float l6 = y.z - hi_part(y.z), l7 = y.w - hi_part(y.w);
  ll.u.x = pack_hi(l0, l1); ll.u.y = pack_hi(l2, l3);
  ll.u.z = pack_hi(l4, l5); ll.u.w = pack_hi(l6, l7);
  h = hh.b; l = ll.b;
}

__device__ __forceinline__ void mfma12(bf16x8 ah0, bf16x8 al0, bf16x8 ah1,
                                       bf16x8 al1, uint4 b0, uint4 b1, uint4 b2,
                                       uint4 b3, f32x4& a00, f32x4& a01,
                                       f32x4& a10, f32x4& a11) {
  U4B8 u0, u1, u2, u3;
  u0.u = b0; u1.u = b1; u2.u = b2; u3.u = b3;   // bh0 bh1 bl0 bl1
  a00 = __builtin_amdgcn_mfma_f32_16x16x32_bf16(ah0, u0.b, a00, 0, 0, 0);
  a00 = __builtin_amdgcn_mfma_f32_16x16x32_bf16(ah0, u2.b, a00, 0, 0, 0);
  a00 = __builtin_amdgcn_mfma_f32_16x16x32_bf16(al0, u0.b, a00, 0, 0, 0);
  a01 = __builtin_amdgcn_mfma_f32_16x16x32_bf16(ah0, u1.b, a01, 0, 0, 0);
  a01 = __builtin_amdgcn_mfma_f32_16x16x32_bf16(ah0, u3.b, a01, 0, 0, 0);
  a01 = __builtin_amdgcn_mfma_f32_16x16x32_bf16(al0, u1.b, a01, 0, 0, 0);
  a10 = __builtin_amdgcn_mfma_f32_16x16x32_bf16(ah1, u0.b, a10, 0, 0, 0);
  a10 = __builtin_amdgcn_mfma_f32_16x16x32_bf16(ah1, u2.b, a10, 0, 0, 0);
  a10 = __builtin_amdgcn_mfma_f32_16x16x32_bf16(al1, u0.b, a10, 0, 0, 0);
  a11 = __builtin_amdgcn_mfma_f32_16x16x32_bf16(ah1, u1.b, a11, 0, 0, 0);
  a11 = __builtin_amdgcn_mfma_f32_16x16x32_bf16(ah1, u3.b, a11, 0, 0, 0);
  a11 = __builtin_amdgcn_mfma_f32_16x16x32_bf16(al1, u1.b, a11, 0, 0, 0);
}

__global__ void pack_w(const float* __restrict__ W) {
  const int tid = blockIdx.x * 256 + threadIdx.x;   // one 16 B record per thread
  if (tid >= NSTEPS * 5 * 64 * 4) return;
  const int v = tid & 3;                 // 0:bh0 1:bh1 2:bl0 3:bl1
  const int lane = (tid >> 2) & 63;
  const int sw = tid >> 8;               // s*5 + wjp
  const int wjp = sw % 5;
  const int s = sw / 5;
  const int col = 32 * wjp + 16 * (v & 1) + (lane & 15);
  const int kb = 32 * s + 8 * (lane >> 4);
  u32 r[4];
#pragma unroll
  for (int jj = 0; jj < 4; ++jj) {
    float x0 = W[(size_t)(kb + 2 * jj) * NN + col];
    float x1 = W[(size_t)(kb + 2 * jj + 1) * NN + col];
    if (v >= 2) { x0 -= hi_part(x0); x1 -= hi_part(x1); }
    r[jj] = pack_hi(x0, x1);
  }
  uint4 o; o.x = r[0]; o.y = r[1]; o.z = r[2]; o.w = r[3];
  *(uint4*)(Wpack_g + (size_t)tid * 16) = o;
}

// async global->LDS DMA, 16 B per lane; lds base wave-uniform + lane*16
#define GLOAD(gp, lp) __builtin_amdgcn_global_load_lds( \
    (const __attribute__((address_space(1))) u32*)(gp), \
    (__attribute__((address_space(3))) u32*)(lp), 16, 0, 0)

// ===================== GEMM: hat partials to workspace =====================
// grid = 1024: rb = bid>>1 (32-row block), ks = bid&1 (K half).
// ~3 blocks/CU resident (16-wave VGPR bucket) -> TLP hides the sync drains.
__global__ __launch_bounds__(GTHREADS, 4) void capsule_gemm(
    const float* __restrict__ X, float* __restrict__ hp) {
  __shared__ __align__(16) char As[2][BMR * 128];   // 2 x 4 KB, XOR-swizzled

  const int t = threadIdx.x;
  const int lane = t & 63;
  const int wjp = t >> 6;                // wave 0..4 = col group
  const int ks = blockIdx.x & 1;
  const int rbase = (blockIdx.x >> 1) * BMR;

  // stage thread mapping (t<256): row = t>>3, dest chunk = t&7,
  // source chunk XOR-swizzled so LDS slot (r,c') holds chunk c = c'^(r&7)
  const int srow = t >> 3;
  const int schk = (t & 7) ^ (srow & 7);
  const float* gA = X + (size_t)(rbase + srow) * KK + ks * (LSTEPS * 32)
                      + schk * 4;

  const int l15 = lane & 15;
  const int q = lane >> 4;
  const int r0 = l15, r1 = l15 + 16;
  const int c0 = 2 * q, c1 = 2 * q + 1;
  const int o00 = (r0 >> 3) * 1024 + (r0 & 7) * 128 + ((c0 ^ (r0 & 7)) << 4);
  const int o01 = (r0 >> 3) * 1024 + (r0 & 7) * 128 + ((c1 ^ (r0 & 7)) << 4);
  const int o10 = (r1 >> 3) * 1024 + (r1 & 7) * 128 + ((c0 ^ (r1 & 7)) << 4);
  const int o11 = (r1 >> 3) * 1024 + (r1 & 7) * 128 + ((c1 ^ (r1 & 7)) << 4);
  const unsigned char* pB = Wpack_g
      + (((size_t)(ks * LSTEPS) * 5 + wjp) * 64 + lane) * 64;

  f32x4 acc00 = {0.f,0.f,0.f,0.f}, acc01 = {0.f,0.f,0.f,0.f};
  f32x4 acc10 = {0.f,0.f,0.f,0.f}, acc11 = {0.f,0.f,0.f,0.f};
  uint4 Bc0, Bc1, Bc2, Bc3, Bn0, Bn1, Bn2, Bn3;

#define BLOADC(P0, P1, P2, P3, S) do {                            \
    const uint4* bp_ = (const uint4*)(pB + (size_t)(S) * BSTEP);  \
    P0 = bp_[0]; P1 = bp_[1]; P2 = bp_[2]; P3 = bp_[3];           \
  } while (0)

#define AMFMA(BUF, P0, P1, P2, P3) do {                           \
    const char* ca_ = As[BUF];                                    \
    float4 A00 = *(const float4*)(ca_ + o00);                     \
    float4 A01 = *(const float4*)(ca_ + o01);                     \
    float4 A10 = *(const float4*)(ca_ + o10);                     \
    float4 A11 = *(const float4*)(ca_ + o11);                     \
    bf16x8 ah0, al0, ah1, al1;                                    \
    split2(A00, A01, ah0, al0);                                   \
    split2(A10, A11, ah1, al1);                                   \
    mfma12(ah0, al0, ah1, al1, P0, P1, P2, P3,                    \
           acc00, acc01, acc10, acc11);                           \
  } while (0)

  if (t < 256) GLOAD(gA, As[0] + t * 16);        // stage step 0
  BLOADC(Bc0, Bc1, Bc2, Bc3, 0);                 // B step 0
  __syncthreads();                               // drains stage+B

#pragma unroll 1
  for (int ii = 0; ii < LSTEPS / 2; ++ii) {
    // even step s = 2ii: stage s+1 -> buf1, prefetch B(s+1), compute buf0/Bc
    if (t < 256) GLOAD(gA + (size_t)(2 * ii + 1) * 32, As[1] + t * 16);
    BLOADC(Bn0, Bn1, Bn2, Bn3, 2 * ii + 1);
    AMFMA(0, Bc0, Bc1, Bc2, Bc3);
    __syncthreads();
    // odd step s = 2ii+1: stage s+1 -> buf0, prefetch B(s+1), compute buf1/Bn
    if (ii != LSTEPS / 2 - 1) {
      if (t < 256) GLOAD(gA + (size_t)(2 * ii + 2) * 32, As[0] + t * 16);
      BLOADC(Bc0, Bc1, Bc2, Bc3, 2 * ii + 2);
    }
    AMFMA(1, Bn0, Bn1, Bn2, Bn3);
    __syncthreads();
  }
#undef BLOADC
#undef AMFMA

  // epilogue: write hat partial. C/D layout: col = lane&15, row = 4q + reg
  float* hb = hp + (size_t)ks * HATN;
#pragma unroll
  for (int r = 0; r < 4; ++r) {
    const int rowb = 4 * q + r;
    const int colb = 32 * wjp + l15;
    hb[(size_t)(rbase + rowb) * NN + colb]           = acc00[r];
    hb[(size_t)(rbase + rowb) * NN + colb + 16]      = acc01[r];
    hb[(size_t)(rbase + rowb + 16) * NN + colb]      = acc10[r];
    hb[(size_t)(rbase + rowb + 16) * NN + colb + 16] = acc11[r];
  }
}

// ===================== routing: 8 lanes per row =====================
__global__ __launch_bounds__(256) void capsule_route(
    const float* __restrict__ hp, float* __restrict__ out) {
  const int gid = blockIdx.x * 256 + threadIdx.x;   // 0 .. 16384*8-1
  const int r = gid >> 3;
  const int d0 = gid & 7;
  const float* h0p = hp + (size_t)r * NN;
  const float* h1p = h0p + HATN;
  float h0[N_CAP], h1[N_CAP];
#pragma unroll
  for (int n = 0; n < N_CAP; ++n) {
    h0[n] = h0p[n * D_CAP + d0]     + h1p[n * D_CAP + d0];
    h1[n] = h0p[n * D_CAP + d0 + 8] + h1p[n * D_CAP + d0 + 8];
  }
  float bb[N_CAP];
#pragma unroll
  for (int n = 0; n < N_CAP; ++n) bb[n] = 0.f;
  float v0 = 0.f, v1 = 0.f;
#pragma unroll
  for (int it = 0; it < 3; ++it) {
    float mx = bb[0];
#pragma unroll
    for (int n = 1; n < N_CAP; ++n) mx = fmaxf(mx, bb[n]);
    float c[N_CAP], se = 0.f;
#pragma unroll
    for (int n = 0; n < N_CAP; ++n) { c[n] = __expf(bb[n] - mx); se += c[n]; }
    const float inv = 1.f / se;
    float s0 = 0.f, s1 = 0.f;
#pragma unroll
    for (int n = 0; n < N_CAP; ++n) { s0 += c[n] * h0[n]; s1 += c[n] * h1[n]; }
    s0 *= inv; s1 *= inv;
    float s2 = s0 * s0 + s1 * s1;
    s2 += __shfl_xor(s2, 1);
    s2 += __shfl_xor(s2, 2);
    s2 += __shfl_xor(s2, 4);
    const float scale = s2 / ((1.f + s2) * sqrtf(s2 + 1e-7f));
    v0 = scale * s0; v1 = scale * s1;
    if (it < 2) {
#pragma unroll
      for (int n = 0; n < N_CAP; ++n) {
        float dd = h0[n] * v0 + h1[n] * v1;
        dd += __shfl_xor(dd, 1);
        dd += __shfl_xor(dd, 2);
        dd += __shfl_xor(dd, 4);
        bb[n] += dd;
      }
    }
  }
  out[(size_t)r * D_CAP + d0] = v0;
  out[(size_t)r * D_CAP + d0 + 8] = v1;
}

extern "C" void kernel_launch(void* const* d_in, const int* in_sizes, int n_in,
                              void* d_out, int out_size, void* d_ws, size_t ws_size,
                              hipStream_t stream) {
  const float* X = (const float*)d_in[0];   // inputs [16384][2048] f32
  const float* W = (const float*)d_in[1];   // kernel [2048][160] f32
  if (n_in >= 2 && in_sizes[0] == KK * NN) {  // defensive: identify by element count
    X = (const float*)d_in[1];
    W = (const float*)d_in[0];
  }
  (void)out_size; (void)ws_size;
  float* hp = (float*)d_ws;                 // 2 hat partials = 21 MB (ws ~512 MB)
  pack_w<<<(NSTEPS * 5 * 64 * 4 + 255) / 256, 256, 0, stream>>>(W);
  capsule_gemm<<<(16384 / BMR) * SPLITK, GTHREADS, 0, stream>>>(X, hp);
  capsule_route<<<16384 * 8 / 256, 256, 0, stream>>>(hp, (float*)d_out);
}